// Round 2
// baseline (266.231 us; speedup 1.0000x reference)
//
#include <hip/hip_runtime.h>

#define SPAT 32768   // 32*32*32
#define BATCH 2
#define GN_EPS 1e-5f

__device__ __forceinline__ void fma4(float4& a, const float4& v, float w) {
    a.x = fmaf(v.x, w, a.x); a.y = fmaf(v.y, w, a.y);
    a.z = fmaf(v.z, w, a.z); a.w = fmaf(v.w, w, a.w);
}

// ---------------- zero the stats buffer (graph-capture-safe, no memset) --------
__global__ __launch_bounds__(64) void k_zero(float* __restrict__ p)
{
    if (threadIdx.x < 32) p[threadIdx.x] = 0.f;
}

// ---------------- 1x1x1 conv: float4 spatial x NO output channels ----------------
// grid: (SPAT/1024, Cout/NO, B), block 256
template <int CIN, int NO, bool RELU>
__global__ __launch_bounds__(256) void k_c1(
    const float* __restrict__ in, const float* __restrict__ w,
    const float* __restrict__ sc, const float* __restrict__ bi,
    float* __restrict__ out, int Cout)
{
    int q = blockIdx.x * 256 + threadIdx.x;
    int s = q * 4;
    int o0 = blockIdx.y * NO, b = blockIdx.z;
    const float* ip = in + (size_t)b * CIN * SPAT + s;
    float4 acc[NO];
#pragma unroll
    for (int i = 0; i < NO; ++i) acc[i] = {0.f, 0.f, 0.f, 0.f};
#pragma unroll 4
    for (int c = 0; c < CIN; ++c) {
        float4 v = *(const float4*)(ip + (size_t)c * SPAT);
#pragma unroll
        for (int i = 0; i < NO; ++i)
            fma4(acc[i], v, w[(o0 + i) * CIN + c]);
    }
#pragma unroll
    for (int i = 0; i < NO; ++i) {
        int o = o0 + i;
        float scale = sc[o], shift = bi[o];
        float4 r = acc[i];
        r.x = r.x * scale + shift; r.y = r.y * scale + shift;
        r.z = r.z * scale + shift; r.w = r.w * scale + shift;
        if (RELU) {
            r.x = fmaxf(r.x, 0.f); r.y = fmaxf(r.y, 0.f);
            r.z = fmaxf(r.z, 0.f); r.w = fmaxf(r.w, 0.f);
        }
        *(float4*)(out + ((size_t)b * Cout + o) * SPAT + s) = r;
    }
}

// ---------------- cv4 stats: compute wk (27 ch/group) in regs, reduce, atomicAdd ----
// grid: (SPAT/1024, 8 groups, B), block 256. NO wk store — SKA recomputes it.
__global__ __launch_bounds__(256) void k_cv4_stats(
    const float* __restrict__ a, const float* __restrict__ w4,
    const float* __restrict__ b4, float* __restrict__ stats)
{
    int q = blockIdx.x * 256 + threadIdx.x;
    int s = q * 4;
    int g = blockIdx.y, b = blockIdx.z;
    const float* ip = a + (size_t)b * 32 * SPAT + s;
    const float* wg = w4 + g * 27 * 32;
    float4 wk[27];
#pragma unroll
    for (int k = 0; k < 27; ++k) {
        float bv = b4[g * 27 + k];
        wk[k] = {bv, bv, bv, bv};
    }
#pragma unroll 2
    for (int c = 0; c < 32; ++c) {
        float4 v = *(const float4*)(ip + (size_t)c * SPAT);
#pragma unroll
        for (int k = 0; k < 27; ++k)
            fma4(wk[k], v, wg[k * 32 + c]);
    }
    float sum = 0.f, ss = 0.f;
#pragma unroll
    for (int k = 0; k < 27; ++k) {
        sum += wk[k].x + wk[k].y + wk[k].z + wk[k].w;
        ss  += wk[k].x * wk[k].x + wk[k].y * wk[k].y
             + wk[k].z * wk[k].z + wk[k].w * wk[k].w;
    }
#pragma unroll
    for (int off = 32; off > 0; off >>= 1) {
        sum += __shfl_down(sum, off, 64);
        ss  += __shfl_down(ss,  off, 64);
    }
    __shared__ float sh[8];
    int wave = threadIdx.x >> 6, lane = threadIdx.x & 63;
    if (lane == 0) { sh[wave * 2] = sum; sh[wave * 2 + 1] = ss; }
    __syncthreads();
    if (threadIdx.x == 0) {
        int bg = b * 8 + g;
        atomicAdd(&stats[bg * 2 + 0], sh[0] + sh[2] + sh[4] + sh[6]);
        atomicAdd(&stats[bg * 2 + 1], sh[1] + sh[3] + sh[5] + sh[7]);
    }
}

// ---------------- SKA fused: recompute wk per kd-slice, normalize, apply ----------
// grid: (SPAT/1024, 8 groups, B), block 256. Thread: 1 spatial quad x 8 channels.
__global__ __launch_bounds__(256) void k_ska(
    const float* __restrict__ x, const float* __restrict__ a1,
    const float* __restrict__ w4, const float* __restrict__ b4,
    const float* __restrict__ stats,
    const float* __restrict__ gn_g, const float* __restrict__ gn_b,
    const float* __restrict__ bn_s, const float* __restrict__ bn_b,
    float* __restrict__ y)
{
    int q = blockIdx.x * 256 + threadIdx.x;
    int s = q * 4;
    int g = blockIdx.y, b = blockIdx.z;
    int bg = b * 8 + g;
    const float N = 27.f * (float)SPAT;
    float mu  = stats[bg * 2 + 0] / N;
    float var = stats[bg * 2 + 1] / N - mu * mu;
    float inv = rsqrtf(var + GN_EPS);
    int d = s >> 10, h = (s >> 5) & 31, w0 = s & 31;
    int lane = threadIdx.x & 63;
    int xl_src = (lane & 56) | ((lane + 7) & 7);   // left neighbor in 8-lane row group
    int xr_src = (lane & 56) | ((lane + 1) & 7);   // right neighbor
    const float* xg = x + ((size_t)(b * 64 + g * 8)) * SPAT;
    const float* ag = a1 + (size_t)b * 32 * SPAT + s;
    const float* wg = w4 + g * 27 * 32;

    float4 acc[8];
    float4 xc[8];
#pragma unroll
    for (int c = 0; c < 8; ++c) acc[c] = {0.f, 0.f, 0.f, 0.f};

#pragma unroll
    for (int kd = 0; kd < 3; ++kd) {
        // ---- recompute wk for the 9 taps of this kd-slice (on-the-fly cv4) ----
        float4 wk9[9];
#pragma unroll
        for (int j = 0; j < 9; ++j) {
            float bv = b4[g * 27 + kd * 9 + j];
            wk9[j] = {bv, bv, bv, bv};
        }
#pragma unroll 4
        for (int c = 0; c < 32; ++c) {
            float4 v = *(const float4*)(ag + (size_t)c * SPAT);
#pragma unroll
            for (int j = 0; j < 9; ++j)
                fma4(wk9[j], v, wg[(kd * 9 + j) * 32 + c]);
        }
        // ---- GroupNorm + affine, in-register: wn = wk*(inv*gg) + (gb - mu*inv*gg) ----
#pragma unroll
        for (int j = 0; j < 9; ++j) {
            int kk = kd * 9 + j;
            float gg = gn_g[g * 27 + kk] * inv;
            float sgb = gn_b[g * 27 + kk] - mu * gg;
            wk9[j].x = wk9[j].x * gg + sgb;
            wk9[j].y = wk9[j].y * gg + sgb;
            wk9[j].z = wk9[j].z * gg + sgb;
            wk9[j].w = wk9[j].w * gg + sgb;
        }
        // ---- apply to 8 channels of x with circular wrap via shuffles ----
        int zd = (d + kd + 31) & 31;
#pragma unroll
        for (int kh = 0; kh < 3; ++kh) {
            int zh = (h + kh + 31) & 31;
            int rowoff = zd * 1024 + zh * 32;
            bool center = (kd == 1) && (kh == 1);
#pragma unroll
            for (int c = 0; c < 8; ++c) {
                float4 m = *(const float4*)(xg + (size_t)c * SPAT + rowoff + w0);
                if (center) xc[c] = m;
                float xl = __shfl(m.w, xl_src, 64);
                float xr = __shfl(m.x, xr_src, 64);
                float win[6] = {xl, m.x, m.y, m.z, m.w, xr};
#pragma unroll
                for (int kw = 0; kw < 3; ++kw) {
                    float4 wn = wk9[kh * 3 + kw];
                    acc[c].x = fmaf(win[0 + kw], wn.x, acc[c].x);
                    acc[c].y = fmaf(win[1 + kw], wn.y, acc[c].y);
                    acc[c].z = fmaf(win[2 + kw], wn.z, acc[c].z);
                    acc[c].w = fmaf(win[3 + kw], wn.w, acc[c].w);
                }
            }
        }
    }
#pragma unroll
    for (int c = 0; c < 8; ++c) {
        int ch = g * 8 + c;
        float bs = bn_s[ch], bb = bn_b[ch];
        float4 r;
        r.x = acc[c].x * bs + bb + xc[c].x;
        r.y = acc[c].y * bs + bb + xc[c].y;
        r.z = acc[c].z * bs + bb + xc[c].z;
        r.w = acc[c].w * bs + bb + xc[c].w;
        *(float4*)(y + ((size_t)(b * 64 + ch)) * SPAT + s) = r;
    }
}

// ---------------- depthwise 5x5x5, zero pad 2, + affine, LDS-tiled ----------------
__global__ __launch_bounds__(256) void k_dw5(
    const float* __restrict__ in, const float* __restrict__ w2,
    const float* __restrict__ s2, const float* __restrict__ b2,
    float* __restrict__ out)
{
    __shared__ float lds[8 * 36 * 40];           // 46,080 B
    int tid = threadIdx.x;
    int d0 = blockIdx.x * 4;
    int c = blockIdx.y, b = blockIdx.z;
    const float* ip = in + ((size_t)(b * 32 + c)) * SPAT;

    float4 z = {0.f, 0.f, 0.f, 0.f};
    for (int i = tid; i < 8 * 36 * 40 / 4; i += 256)
        ((float4*)lds)[i] = z;
    __syncthreads();
    for (int i = tid; i < 8 * 256; i += 256) {
        int p = i >> 8, rem = i & 255;
        int r = rem >> 3, c4 = (rem & 7) * 4;
        int d = d0 - 2 + p;
        if (d >= 0 && d < 32) {
            float4 v = *(const float4*)(ip + d * 1024 + r * 32 + c4);
            *(float4*)&lds[p * 1440 + (r + 2) * 40 + (c4 + 4)] = v;
        }
    }
    __syncthreads();

    float scl = s2[c], shf = b2[c];
    const float* wt = w2 + c * 125;
#pragma unroll
    for (int k = 0; k < 4; ++k) {
        int j = tid + k * 256;
        int pd = j >> 8, rem = j & 255;
        int hr = rem >> 3, w4i = (rem & 7) * 4;
        float4 acc = {0.f, 0.f, 0.f, 0.f};
#pragma unroll
        for (int kd = 0; kd < 5; ++kd) {
            const float* pl = &lds[(pd + kd) * 1440];
#pragma unroll
            for (int kh = 0; kh < 5; ++kh) {
                const float* row = pl + (hr + kh) * 40 + w4i;
                float4 r0 = *(const float4*)(row);
                float4 r1 = *(const float4*)(row + 4);
                float4 r2 = *(const float4*)(row + 8);
                float win[12] = {r0.x, r0.y, r0.z, r0.w,
                                 r1.x, r1.y, r1.z, r1.w,
                                 r2.x, r2.y, r2.z, r2.w};
#pragma unroll
                for (int kw = 0; kw < 5; ++kw) {
                    float wv = wt[kd * 25 + kh * 5 + kw];
                    acc.x = fmaf(wv, win[2 + 0 + kw], acc.x);
                    acc.y = fmaf(wv, win[2 + 1 + kw], acc.y);
                    acc.z = fmaf(wv, win[2 + 2 + kw], acc.z);
                    acc.w = fmaf(wv, win[2 + 3 + kw], acc.w);
                }
            }
        }
        acc.x = acc.x * scl + shf; acc.y = acc.y * scl + shf;
        acc.z = acc.z * scl + shf; acc.w = acc.w * scl + shf;
        *(float4*)(out + ((size_t)(b * 32 + c)) * SPAT
                   + (d0 + pd) * 1024 + hr * 32 + w4i) = acc;
    }
}

// ---------------- pw2 (128->64) + affine + residual, NO outputs/thread ----------------
template <int NO>
__global__ __launch_bounds__(256) void k_pw2_out(
    const float* __restrict__ f1, const float* __restrict__ w,
    const float* __restrict__ sc, const float* __restrict__ bi,
    const float* __restrict__ yres, float* __restrict__ out)
{
    int q = blockIdx.x * 256 + threadIdx.x;
    int s = q * 4;
    int o0 = blockIdx.y * NO, b = blockIdx.z;
    const float* ip = f1 + (size_t)b * 128 * SPAT + s;
    float4 acc[NO];
#pragma unroll
    for (int i = 0; i < NO; ++i) acc[i] = {0.f, 0.f, 0.f, 0.f};
#pragma unroll 4
    for (int c = 0; c < 128; ++c) {
        float4 v = *(const float4*)(ip + (size_t)c * SPAT);
#pragma unroll
        for (int i = 0; i < NO; ++i)
            fma4(acc[i], v, w[(o0 + i) * 128 + c]);
    }
#pragma unroll
    for (int i = 0; i < NO; ++i) {
        int o = o0 + i;
        float scale = sc[o], shift = bi[o];
        float4 yv = *(const float4*)(yres + ((size_t)(b * 64 + o)) * SPAT + s);
        float4 r = acc[i];
        r.x = r.x * scale + shift + yv.x;
        r.y = r.y * scale + shift + yv.y;
        r.z = r.z * scale + shift + yv.z;
        r.w = r.w * scale + shift + yv.w;
        *(float4*)(out + ((size_t)(b * 64 + o)) * SPAT + s) = r;
    }
}

extern "C" void kernel_launch(void* const* d_in, const int* in_sizes, int n_in,
                              void* d_out, int out_size, void* d_ws, size_t ws_size,
                              hipStream_t stream)
{
    const float* x     = (const float*)d_in[0];
    const float* w1    = (const float*)d_in[1];
    const float* s1    = (const float*)d_in[2];
    const float* b1    = (const float*)d_in[3];
    const float* w2    = (const float*)d_in[4];
    const float* s2    = (const float*)d_in[5];
    const float* b2    = (const float*)d_in[6];
    const float* w3    = (const float*)d_in[7];
    const float* s3    = (const float*)d_in[8];
    const float* b3    = (const float*)d_in[9];
    const float* w4    = (const float*)d_in[10];
    const float* b4    = (const float*)d_in[11];
    const float* gn_g  = (const float*)d_in[12];
    const float* gn_b  = (const float*)d_in[13];
    const float* bn_s  = (const float*)d_in[14];
    const float* bn_b  = (const float*)d_in[15];
    const float* pw1_w = (const float*)d_in[16];
    const float* pw1_s = (const float*)d_in[17];
    const float* pw1_b = (const float*)d_in[18];
    const float* pw2_w = (const float*)d_in[19];
    const float* pw2_s = (const float*)d_in[20];
    const float* pw2_b = (const float*)d_in[21];

    // Workspace (64 MB + 128 B), all disjoint — wk is never materialized:
    float* ws    = (float*)d_ws;
    float* a1    = ws;                                   // 2*32*S  =  8 MB
    float* a2    = a1 + (size_t)BATCH * 32 * SPAT;       // 2*32*S  =  8 MB
    float* yb    = a2 + (size_t)BATCH * 32 * SPAT;       // 2*64*S  = 16 MB
    float* f1    = yb + (size_t)BATCH * 64 * SPAT;       // 2*128*S = 32 MB
    float* stats = f1 + (size_t)BATCH * 128 * SPAT;      // 16*2 floats

    dim3 blk(256);
    // zero GN stats accumulators (in-stream, graph-capture-safe)
    k_zero<<<dim3(1), dim3(64), 0, stream>>>(stats);
    // cv1 + BN + ReLU : 64 -> 32  (8 outputs/thread)
    k_c1<64, 8, true><<<dim3(SPAT / 1024, 4, BATCH), blk, 0, stream>>>(
        x, w1, s1, b1, a1, 32);
    // dw 5^3 + BN (LDS-tiled)
    k_dw5<<<dim3(8, 32, BATCH), blk, 0, stream>>>(a1, w2, s2, b2, a2);
    // cv3 + BN + ReLU : 32 -> 32  (8 outputs/thread)
    k_c1<32, 8, true><<<dim3(SPAT / 1024, 4, BATCH), blk, 0, stream>>>(
        a2, w3, s3, b3, a1, 32);
    // cv4 + bias + GN stats, wk kept in registers only
    k_cv4_stats<<<dim3(SPAT / 1024, 8, BATCH), blk, 0, stream>>>(
        a1, w4, b4, stats);
    // SKA: recompute wk per kd-slice + GN + BN + residual -> y
    k_ska<<<dim3(SPAT / 1024, 8, BATCH), blk, 0, stream>>>(
        x, a1, w4, b4, stats, gn_g, gn_b, bn_s, bn_b, yb);
    // pw1 + BN + ReLU : 64 -> 128  (16 outputs/thread)
    k_c1<64, 16, true><<<dim3(SPAT / 1024, 8, BATCH), blk, 0, stream>>>(
        yb, pw1_w, pw1_s, pw1_b, f1, 128);
    // pw2 + BN + residual -> out  (16 outputs/thread)
    k_pw2_out<16><<<dim3(SPAT / 1024, 4, BATCH), blk, 0, stream>>>(
        f1, pw2_w, pw2_s, pw2_b, yb, (float*)d_out);
}